// Round 3
// baseline (129.022 us; speedup 1.0000x reference)
//
#include <hip/hip_runtime.h>
#include <hip/hip_bf16.h>
#include <stdint.h>

using bf16 = __hip_bfloat16;
typedef __attribute__((ext_vector_type(8))) short bf16x8;   // 8 bf16 = 4 VGPRs
typedef __attribute__((ext_vector_type(4))) float f32x4;

static __device__ __forceinline__ float b2f(short u) {
  union { float f; unsigned int i; } c;
  c.i = ((unsigned int)(unsigned short)u) << 16;
  return c.f;
}
static __device__ __forceinline__ short f2b(float f) {
  return (short)__bfloat16_as_ushort(__float2bfloat16(f));
}

// ---------------------------------------------------------------------------
// async global->LDS, 16B per lane (global_load_lds_dwordx4).
// ---------------------------------------------------------------------------
__device__ __forceinline__ void async16(const void* g, void* lds) {
  __builtin_amdgcn_global_load_lds(
      (const __attribute__((address_space(1))) void*)g,
      (__attribute__((address_space(3))) void*)lds, 16, 0, 0);
}

// ---------------------------------------------------------------------------
// Kron-expanded DOWN weight, transposed bf16: wdT[n][k], n<512, k<2048
// ---------------------------------------------------------------------------
__global__ void build_wdT(const float* __restrict__ phm,
                          const float* __restrict__ Wd,
                          bf16* __restrict__ out) {
  int idx = blockIdx.x * 256 + threadIdx.x;
  if (idx >= 512 * 2048) return;
  int n = idx >> 11, k = idx & 2047;
  int r = n >> 7, s = n & 127;
  int p = k >> 9, q = k & 511;
  float v = 0.f;
#pragma unroll
  for (int i = 0; i < 4; ++i)
    v += phm[i * 16 + p * 4 + r] * Wd[i * 65536 + q * 128 + s];
  out[idx] = (bf16)v;
}

// ---------------------------------------------------------------------------
// Kron-expanded UP weight, transposed bf16: wuT[d][b], d<2048, b<512
// ---------------------------------------------------------------------------
__global__ void build_wuT(const float* __restrict__ phm,
                          const float* __restrict__ Wu,
                          bf16* __restrict__ out) {
  int idx = blockIdx.x * 256 + threadIdx.x;
  if (idx >= 2048 * 512) return;
  int d = idx >> 9, b = idx & 511;
  int r = d >> 9, s = d & 511;
  int p = b >> 7, q = b & 127;
  float v = 0.f;
#pragma unroll
  for (int i = 0; i < 4; ++i)
    v += phm[i * 16 + p * 4 + r] * Wu[i * 65536 + q * 512 + s];
  out[idx] = (bf16)v;
}

// ---------------------------------------------------------------------------
// x (f32) -> bf16
// ---------------------------------------------------------------------------
__global__ void cast_f32_bf16(const float* __restrict__ in,
                              bf16* __restrict__ out, int n4) {
  int i = blockIdx.x * 256 + threadIdx.x;
  if (i >= n4) return;
  float4 v = reinterpret_cast<const float4*>(in)[i];
  ushort4 o;
  o.x = __bfloat16_as_ushort(__float2bfloat16(v.x));
  o.y = __bfloat16_as_ushort(__float2bfloat16(v.y));
  o.z = __bfloat16_as_ushort(__float2bfloat16(v.z));
  o.w = __bfloat16_as_ushort(__float2bfloat16(v.w));
  reinterpret_cast<ushort4*>(out)[i] = o;
}

// ---------------------------------------------------------------------------
// z = relu(sum_c P[c] + b_down) -> bf16.   P: 4 x [8192][512] bf16 partials
// ---------------------------------------------------------------------------
__global__ void zred(const bf16* __restrict__ P, const float* __restrict__ bias,
                     bf16* __restrict__ z) {
  int i = blockIdx.x * 256 + threadIdx.x;        // vec8 index
  const int NV = 8192 * 512 / 8;
  if (i >= NV) return;
  const size_t CS = (size_t)NV;                  // chunk stride in vec8 units
  bf16x8 v0 = ((const bf16x8*)P)[i];
  bf16x8 v1 = ((const bf16x8*)P)[i + CS];
  bf16x8 v2 = ((const bf16x8*)P)[i + 2 * CS];
  bf16x8 v3 = ((const bf16x8*)P)[i + 3 * CS];
  int c0 = (i * 8) & 511;
  bf16x8 o;
#pragma unroll
  for (int j = 0; j < 8; ++j) {
    float t = b2f(v0[j]) + b2f(v1[j]) + b2f(v2[j]) + b2f(v3[j]) + bias[c0 + j];
    o[j] = f2b(t > 0.f ? t : 0.f);
  }
  ((bf16x8*)z)[i] = o;
}

// ---------------------------------------------------------------------------
// C = A[.][lda-strided] * Bt^T (+bias).
// EPI=0: bias+relu -> bf16 ; EPI=1: bias -> f32 ; EPI=2: raw -> bf16 partial
// 128x128 tile, BK=32, 4 waves, 4x4 16x16x32 frags/wave, dbuf prefetch.
// Grid linear; bijective XCD swizzle (gridDim.x % 8 == 0 required).
// Split-K via chunk = bid/(nbx*nby): offsets K by chunk*Klen, C by cStride.
// ---------------------------------------------------------------------------
template <int EPI>
__global__ __launch_bounds__(256)
void gemm_bt(const bf16* __restrict__ A, const bf16* __restrict__ Bt,
             const float* __restrict__ bias, void* __restrict__ Cout,
             int lda, int ldb, int Klen, int N, int nbx, int nby,
             size_t cStrideBytes) {
  constexpr int BM = 128, BN = 128, BK = 32;
  __shared__ bf16 Ash[2][BM * BK];
  __shared__ bf16 Bsh[2][BN * BK];

  // XCD swizzle (bijective: gridDim.x multiple of 8)
  int bid = blockIdx.x;
  int q = gridDim.x >> 3;
  bid = (bid & 7) * q + (bid >> 3);
  const int bx = bid % nbx;
  const int t1 = bid / nbx;
  const int by = t1 % nby;
  const int chunk = t1 / nby;
  const int bm = bx * BM;
  const int bn = by * BN;
  const int koff = chunk * Klen;
  char* Cb = (char*)Cout + (size_t)chunk * cStrideBytes;

  const int tid  = threadIdx.x;
  const int lane = tid & 63;
  const int wave = tid >> 6;
  const int wm = (wave >> 1) * 64;
  const int wn = (wave & 1) * 64;
  const int rl = lane & 15;
  const int sw = lane >> 4;

  f32x4 acc[4][4] = {};

#define STAGE(buf, kk)                                                        \
  {                                                                           \
    _Pragma("unroll")                                                         \
    for (int is = 0; is < 2; ++is) {                                          \
      int idx = is * 256 + tid;                                               \
      int r = idx >> 2, s = idx & 3;                                          \
      async16(A + (size_t)(bm + r) * lda + (kk) + ((s ^ (r & 3)) * 8),        \
              &Ash[buf][idx * 8]);                                            \
    }                                                                         \
    _Pragma("unroll")                                                         \
    for (int is = 0; is < 2; ++is) {                                          \
      int idx = is * 256 + tid;                                               \
      int r = idx >> 2, s = idx & 3;                                          \
      async16(Bt + (size_t)(bn + r) * ldb + (kk) + ((s ^ (r & 3)) * 8),       \
              &Bsh[buf][idx * 8]);                                            \
    }                                                                         \
  }

  const int nt = Klen / BK;

  STAGE(0, koff);
  __syncthreads();

  for (int t = 0; t < nt; ++t) {
    const int cur = t & 1;
    if (t + 1 < nt) STAGE(cur ^ 1, koff + (t + 1) * BK);

    bf16x8 af[4], bfr[4];
#pragma unroll
    for (int m = 0; m < 4; ++m) {
      int rr = wm + m * 16 + rl;
      af[m] = *(const bf16x8*)(&Ash[cur][rr * BK + ((sw ^ (rl & 3)) * 8)]);
    }
#pragma unroll
    for (int n = 0; n < 4; ++n) {
      int rr = wn + n * 16 + rl;
      bfr[n] = *(const bf16x8*)(&Bsh[cur][rr * BK + ((sw ^ (rl & 3)) * 8)]);
    }

    __builtin_amdgcn_s_setprio(1);
#pragma unroll
    for (int m = 0; m < 4; ++m)
#pragma unroll
      for (int n = 0; n < 4; ++n)
        acc[m][n] = __builtin_amdgcn_mfma_f32_16x16x32_bf16(af[m], bfr[n],
                                                            acc[m][n], 0, 0, 0);
    __builtin_amdgcn_s_setprio(0);

    __syncthreads();
  }
#undef STAGE

  // C/D layout: col = lane&15, row = (lane>>4)*4 + j
  const int rq = sw * 4;
#pragma unroll
  for (int n = 0; n < 4; ++n) {
    int gc = bn + wn + n * 16 + rl;
    float bv = (EPI == 2) ? 0.f : bias[gc];
#pragma unroll
    for (int m = 0; m < 4; ++m) {
      int gr0 = bm + wm + m * 16 + rq;
#pragma unroll
      for (int j = 0; j < 4; ++j) {
        float v = acc[m][n][j] + bv;
        if constexpr (EPI == 0) {
          v = v > 0.f ? v : 0.f;
          ((bf16*)Cb)[(size_t)(gr0 + j) * N + gc] = __float2bfloat16(v);
        } else if constexpr (EPI == 1) {
          ((float*)Cb)[(size_t)(gr0 + j) * N + gc] = v;
        } else {
          ((bf16*)Cb)[(size_t)(gr0 + j) * N + gc] = __float2bfloat16(v);
        }
      }
    }
  }
}

// ---------------------------------------------------------------------------
extern "C" void kernel_launch(void* const* d_in, const int* in_sizes, int n_in,
                              void* d_out, int out_size, void* d_ws, size_t ws_size,
                              hipStream_t stream) {
  const float* x      = (const float*)d_in[0];   // [8192,2048]
  const float* phm    = (const float*)d_in[1];   // [4,4,4]
  const float* W_down = (const float*)d_in[2];   // [4,512,128]
  const float* b_down = (const float*)d_in[3];   // [512]
  const float* W_up   = (const float*)d_in[4];   // [4,128,512]
  const float* b_up   = (const float*)d_in[5];   // [2048]
  float* out = (float*)d_out;                    // [8192,2048] f32

  const int T = 8192, D = 2048, B = 512;
  const size_t MB = 1024 * 1024;

  char* ws = (char*)d_ws;
  bf16* xb  = (bf16*)(ws);                 // 32 MB  [8192][2048]
  bf16* wdT = (bf16*)(ws + 32 * MB);       //  2 MB  [512][2048]
  bf16* wuT = (bf16*)(ws + 34 * MB);       //  2 MB  [2048][512]
  bf16* z   = (bf16*)(ws + 36 * MB);       //  8 MB  [8192][512]
  bf16* P   = (bf16*)(ws + 44 * MB);       // 32 MB  4 x [8192][512] partials

  // prep
  cast_f32_bf16<<<dim3((T * D / 4 + 255) / 256), dim3(256), 0, stream>>>(x, xb, T * D / 4);
  build_wdT<<<dim3((B * D + 255) / 256), dim3(256), 0, stream>>>(phm, W_down, wdT);
  build_wuT<<<dim3((D * B + 255) / 256), dim3(256), 0, stream>>>(phm, W_up, wuT);

  if (ws_size >= 76 * MB) {
    // GEMM1 split-K x4: partials P[c] = x @ Wd (K chunk c), grid 64x4x4 = 1024
    gemm_bt<2><<<dim3(1024), dim3(256), 0, stream>>>(
        xb, wdT, b_down, P, D, D, 512, B, 64, 4, (size_t)T * B * sizeof(bf16));
    // z = relu(sum P + b_down)
    zred<<<dim3(T * B / 8 / 256), dim3(256), 0, stream>>>(P, b_down, z);
  } else {
    // fallback: single-pass GEMM1
    gemm_bt<0><<<dim3(256), dim3(256), 0, stream>>>(
        xb, wdT, b_down, z, D, D, D, B, 64, 4, 0);
  }

  // out = z @ Wu + b_up   [8192,2048] f32, grid 64x16 = 1024
  gemm_bt<1><<<dim3(1024), dim3(256), 0, stream>>>(
      z, wuT, b_up, out, B, B, B, D, 64, 16, 0);
}